// Round 14
// baseline (447.683 us; speedup 1.0000x reference)
//
#include <hip/hip_runtime.h>

// BeamDelay2AntFreq: (256,32,8,4,2,48) complex -> ifft4(V) -> ifft8(H) -> fft48(t),
// fftshifts folded into (-1)^{h+v+f}; ortho norm 1/sqrt(1536).
// OUTPUT: interleaved bf16 pairs IMAG FIRST: dword = im | (re<<16), (b,c,row,f) order.
// R14: time-DFT factored 48 = 4x12 with S[b][j] shared across the 4 c-threads via
// LDS (3x fewer FLOPs, no VGPR spill), occupancy 2->3 blocks/CU.

namespace {

constexpr int RP = 52;       // padded LDS row stride for 48-float rows (16B aligned)
constexpr int SP = 49;       // S-buffer row stride (bank spread for broadcast reads)
constexpr float NORM = 0.02551551815399144f;  // 1/sqrt(1536)

constexpr float COS48[48] = {
  1.0f,        0.99144486f,  0.96592583f,  0.92387953f,  0.86602540f,  0.79335334f,
  0.70710678f, 0.60876143f,  0.5f,         0.38268343f,  0.25881905f,  0.13052619f,
  0.0f,       -0.13052619f, -0.25881905f, -0.38268343f, -0.5f,        -0.60876143f,
 -0.70710678f,-0.79335334f, -0.86602540f, -0.92387953f, -0.96592583f, -0.99144486f,
 -1.0f,       -0.99144486f, -0.96592583f, -0.92387953f, -0.86602540f, -0.79335334f,
 -0.70710678f,-0.60876143f, -0.5f,        -0.38268343f, -0.25881905f, -0.13052619f,
  0.0f,        0.13052619f,  0.25881905f,  0.38268343f,  0.5f,         0.60876143f,
  0.70710678f, 0.79335334f,  0.86602540f,  0.92387953f,  0.96592583f,  0.99144486f
};
constexpr float SIN48[48] = {
  0.0f,        0.13052619f,  0.25881905f,  0.38268343f,  0.5f,         0.60876143f,
  0.70710678f, 0.79335334f,  0.86602540f,  0.92387953f,  0.96592583f,  0.99144486f,
  1.0f,        0.99144486f,  0.96592583f,  0.92387953f,  0.86602540f,  0.79335334f,
  0.70710678f, 0.60876143f,  0.5f,         0.38268343f,  0.25881905f,  0.13052619f,
  0.0f,       -0.13052619f, -0.25881905f, -0.38268343f, -0.5f,        -0.60876143f,
 -0.70710678f,-0.79335334f, -0.86602540f, -0.92387953f, -0.96592583f, -0.99144486f,
 -1.0f,       -0.99144486f, -0.96592583f, -0.92387953f, -0.86602540f, -0.79335334f,
 -0.70710678f,-0.60876143f, -0.5f,        -0.38268343f, -0.25881905f, -0.13052619f
};

constexpr float W8R_TAB[8] = {1.0f, 0.70710678f, 0.0f, -0.70710678f, -1.0f, -0.70710678f, 0.0f, 0.70710678f};
constexpr float W8I_TAB[8] = {0.0f, 0.70710678f, 1.0f,  0.70710678f,  0.0f, -0.70710678f, -1.0f, -0.70710678f};

__device__ __forceinline__ unsigned bf16_rne(float x) {
  unsigned u = __float_as_uint(x);
  u += 0x7FFFu + ((u >> 16) & 1u);
  return u >> 16;
}

__device__ __forceinline__ void ld4(const float* p, float* d) {
  float4 v = *reinterpret_cast<const float4*>(p);
  d[0] = v.x; d[1] = v.y; d[2] = v.z; d[3] = v.w;
}
__device__ __forceinline__ void st4(float* p, const float* s) {
  *reinterpret_cast<float4*>(p) = make_float4(s[0], s[1], s[2], s[3]);
}

__global__ __launch_bounds__(256, 3)
void bd2af_kernel(const float* __restrict__ xr, const float* __restrict__ xi,
                  unsigned* __restrict__ out, int nbc) {
  __shared__ __align__(16) float Ar[64 * RP], Ai[64 * RP];   // X -> Y -> out staging
  __shared__ __align__(16) float Br[64 * RP], Bi[64 * RP];   // T1 -> S buffer
  __shared__ float w8r[8], w8i[8];

  const int tid = threadIdx.x;
  const int bc = blockIdx.x;
  if (bc >= nbc) return;

  if (tid < 8) { w8r[tid] = W8R_TAB[tid]; w8i[tid] = W8I_TAB[tid]; }

  // ---- global -> LDS (rows of 48 padded to 52) ----
  {
    const float4* gr = reinterpret_cast<const float4*>(xr) + (size_t)bc * 768;
    const float4* gi = reinterpret_cast<const float4*>(xi) + (size_t)bc * 768;
#pragma unroll
    for (int k = 0; k < 3; ++k) {
      const int o4 = tid + 256 * k;
      const float4 vr = gr[o4];
      const float4 vi = gi[o4];
      const int o = o4 * 4;
      const int row = o / 48;
      const int a = row * RP + (o - row * 48);
      *reinterpret_cast<float4*>(&Ar[a]) = vr;
      *reinterpret_cast<float4*>(&Ai[a]) = vi;
    }
  }
  __syncthreads();

  const int c  = tid & 3;          // t/freq chunk
  const int t0 = c * 12;
  const int p  = (tid >> 2) & 1;
  const int vq = (tid >> 3) & 3;
  const int hq = tid >> 5;

  // ---- V pass: T1[H][v'][p][t] = sum_V X[H][V][p][t] * i^(V*v') ----
  {
    float ar[12], ai2[12];
#pragma unroll
    for (int k = 0; k < 12; ++k) { ar[k] = 0.f; ai2[k] = 0.f; }
#pragma unroll
    for (int V = 0; V < 4; ++V) {
      const int m = (V * vq) & 3;
      const float wr = (m == 0) ? 1.f : ((m == 2) ? -1.f : 0.f);
      const float wi = (m == 1) ? 1.f : ((m == 3) ? -1.f : 0.f);
      const int rowi = (hq * 4 + V) * 2 + p;
      const float* sr = &Ar[rowi * RP + t0];
      const float* si = &Ai[rowi * RP + t0];
      float yr[12], yi4[12];
      ld4(sr, yr); ld4(sr + 4, yr + 4); ld4(sr + 8, yr + 8);
      ld4(si, yi4); ld4(si + 4, yi4 + 4); ld4(si + 8, yi4 + 8);
#pragma unroll
      for (int k = 0; k < 12; ++k) {
        ar[k]  += yr[k] * wr - yi4[k] * wi;
        ai2[k] += yr[k] * wi + yi4[k] * wr;
      }
    }
    const int rowo = (hq * 4 + vq) * 2 + p;
    float* dr = &Br[rowo * RP + t0];
    float* di = &Bi[rowo * RP + t0];
    st4(dr, ar); st4(dr + 4, ar + 4); st4(dr + 8, ar + 8);
    st4(di, ai2); st4(di + 4, ai2 + 4); st4(di + 8, ai2 + 8);
  }
  __syncthreads();

  // ---- H pass: Y[h'][v'][p][t] = (-1)^{h'+v'} * sum_H T1[H][v'][p][t] * w8[(H*h')%8] ----
  {
    float ar[12], ai2[12];
#pragma unroll
    for (int k = 0; k < 12; ++k) { ar[k] = 0.f; ai2[k] = 0.f; }
#pragma unroll
    for (int H = 0; H < 8; ++H) {
      const int m = (H * hq) & 7;
      const float wr = w8r[m];
      const float wi = w8i[m];
      const int rowi = (H * 4 + vq) * 2 + p;
      const float* sr = &Br[rowi * RP + t0];
      const float* si = &Bi[rowi * RP + t0];
      float yr[12], yi4[12];
      ld4(sr, yr); ld4(sr + 4, yr + 4); ld4(sr + 8, yr + 8);
      ld4(si, yi4); ld4(si + 4, yi4 + 4); ld4(si + 8, yi4 + 8);
#pragma unroll
      for (int k = 0; k < 12; ++k) {
        ar[k]  += yr[k] * wr - yi4[k] * wi;
        ai2[k] += yr[k] * wi + yi4[k] * wr;
      }
    }
    const float sgn = ((hq + vq) & 1) ? -1.f : 1.f;
    const int rowo = (hq * 4 + vq) * 2 + p;
    float* dr = &Ar[rowo * RP + t0];
    float* di = &Ai[rowo * RP + t0];
#pragma unroll
    for (int k = 0; k < 12; ++k) { ar[k] *= sgn; ai2[k] *= sgn; }
    st4(dr, ar); st4(dr + 4, ar + 4); st4(dr + 8, ar + 8);
    st4(di, ai2); st4(di + 4, ai2 + 4); st4(di + 8, ai2 + 8);
  }
  __syncthreads();

  // ---- time DFT, radix 48 = 4 x 12 ----
  // out[12c+j] = sum_b (-i)^{bc} * W48^{bj} * S[b][j],  S[b][j] = sum_a z[4a+b] W12^{aj}
  float* Sr = Br;   // S buffer overlays T1 (dead): [row][b*12+j], stride SP=49
  float* Si = Bi;

  // Phase A: thread (r, b) computes S[b][0..11] for its row from Y (in Ar/Ai)
  {
    const int r = tid >> 2;
    const int b = tid & 3;
    float z_r[12], z_i[12];
#pragma unroll
    for (int a = 0; a < 12; ++a) {
      z_r[a] = Ar[r * RP + 4 * a + b];
      z_i[a] = Ai[r * RP + 4 * a + b];
    }
    float s_r[12], s_i[12];
#pragma unroll
    for (int j = 0; j < 12; ++j) { s_r[j] = 0.f; s_i[j] = 0.f; }
#pragma unroll
    for (int a = 0; a < 12; ++a) {
#pragma unroll
      for (int j = 0; j < 12; ++j) {
        const int k = (4 * a * j) % 48;
        const float wr = COS48[k];
        const float wi = -SIN48[k];
        s_r[j] += z_r[a] * wr - z_i[a] * wi;
        s_i[j] += z_r[a] * wi + z_i[a] * wr;
      }
    }
#pragma unroll
    for (int j = 0; j < 12; ++j) {
      Sr[r * SP + b * 12 + j] = s_r[j];
      Si[r * SP + b * 12 + j] = s_i[j];
    }
  }
  __syncthreads();

  // Phase B: thread (r, c) combines 4 b-slices into out[12c+j], packs bf16
  {
    const int r = tid >> 2;
    // (-i)^c rotation constants
    const float a1r = (c == 0) ? 1.f : ((c == 2) ? -1.f : 0.f);
    const float a1i = (c == 1) ? -1.f : ((c == 3) ? 1.f : 0.f);
    const float s2  = (c & 1) ? -1.f : 1.f;
    float or_[12], oi_[12];
    // b = 0 (twiddle 1)
#pragma unroll
    for (int j = 0; j < 12; ++j) {
      or_[j] = Sr[r * SP + j];
      oi_[j] = Si[r * SP + j];
    }
    // b = 1: T = S[1][j]*W48^j ; acc += (-i)^c * T
#pragma unroll
    for (int j = 0; j < 12; ++j) {
      const float wr = COS48[j], wi = -SIN48[j];
      const float sr = Sr[r * SP + 12 + j], si = Si[r * SP + 12 + j];
      const float tr = sr * wr - si * wi, ti = sr * wi + si * wr;
      or_[j] += a1r * tr - a1i * ti;
      oi_[j] += a1r * ti + a1i * tr;
    }
    // b = 2: T = S[2][j]*W48^{2j} ; acc += (-1)^c * T
#pragma unroll
    for (int j = 0; j < 12; ++j) {
      const float wr = COS48[(2 * j) % 48], wi = -SIN48[(2 * j) % 48];
      const float sr = Sr[r * SP + 24 + j], si = Si[r * SP + 24 + j];
      const float tr = sr * wr - si * wi, ti = sr * wi + si * wr;
      or_[j] += s2 * tr;
      oi_[j] += s2 * ti;
    }
    // b = 3: T = S[3][j]*W48^{3j} ; acc += (i)^c * T = (a1r, -a1i) * T
#pragma unroll
    for (int j = 0; j < 12; ++j) {
      const float wr = COS48[(3 * j) % 48], wi = -SIN48[(3 * j) % 48];
      const float sr = Sr[r * SP + 36 + j], si = Si[r * SP + 36 + j];
      const float tr = sr * wr - si * wi, ti = sr * wi + si * wr;
      or_[j] += a1r * tr + a1i * ti;
      oi_[j] += a1r * ti - a1i * tr;
    }
    // pack: f = 12c + j, (-1)^f = (-1)^j; staging overlays Ar (Y dead)
    unsigned* obuf = reinterpret_cast<unsigned*>(Ar);
#pragma unroll
    for (int j = 0; j < 12; ++j) {
      const float s = (j & 1) ? -NORM : NORM;
      obuf[r * 48 + c * 12 + j] = bf16_rne(oi_[j] * s) | (bf16_rne(or_[j] * s) << 16);
    }
  }
  __syncthreads();

  // ---- coalesced store: 3072 dwords = 768 uint4 per block ----
  {
    const uint4* ob = reinterpret_cast<const uint4*>(Ar);
    uint4* og = reinterpret_cast<uint4*>(out) + (size_t)bc * 768;
#pragma unroll
    for (int k = 0; k < 3; ++k) {
      const int o4 = tid + 256 * k;
      og[o4] = ob[o4];
    }
  }
}

} // namespace

extern "C" void kernel_launch(void* const* d_in, const int* in_sizes, int n_in,
                              void* d_out, int out_size, void* d_ws, size_t ws_size,
                              hipStream_t stream) {
  const float* xr = (const float*)d_in[0];   // dict order: x_real first
  const float* xi = (const float*)d_in[1];
  unsigned* out = (unsigned*)d_out;          // dword = im(bf16) | re(bf16)<<16
  const int nbc = in_sizes[0] / 3072;        // 8192 blocks of (8*4*2*48)
  bd2af_kernel<<<nbc, 256, 0, stream>>>(xr, xi, out, nbc);
}

// Round 17
// 113.778 us; speedup vs baseline: 3.9347x; 3.9347x over previous
//
#include <hip/hip_runtime.h>

// BeamDelay2AntFreq: (256,32,8,4,2,48) complex -> ifft4(V) -> ifft8(H) -> fft48(t),
// fftshifts folded into (-1)^{h+v+f}; ortho norm 1/sqrt(1536).
// OUTPUT: interleaved bf16 pairs IMAG FIRST: dword = im | (re<<16), (b,c,row,f) order.
// R17 = R15 resubmission (R15/R16 were infra failures): all address-taken local
// arrays removed (ld4/st4 helpers forced scratch -> 1.7GB spill traffic).

namespace {

constexpr int RP = 52;       // padded LDS row stride for 48-float rows
constexpr int SP = 49;       // S-buffer row stride
constexpr float NORM = 0.02551551815399144f;  // 1/sqrt(1536)

constexpr float COS48[48] = {
  1.0f,        0.99144486f,  0.96592583f,  0.92387953f,  0.86602540f,  0.79335334f,
  0.70710678f, 0.60876143f,  0.5f,         0.38268343f,  0.25881905f,  0.13052619f,
  0.0f,       -0.13052619f, -0.25881905f, -0.38268343f, -0.5f,        -0.60876143f,
 -0.70710678f,-0.79335334f, -0.86602540f, -0.92387953f, -0.96592583f, -0.99144486f,
 -1.0f,       -0.99144486f, -0.96592583f, -0.92387953f, -0.86602540f, -0.79335334f,
 -0.70710678f,-0.60876143f, -0.5f,        -0.38268343f, -0.25881905f, -0.13052619f,
  0.0f,        0.13052619f,  0.25881905f,  0.38268343f,  0.5f,         0.60876143f,
  0.70710678f, 0.79335334f,  0.86602540f,  0.92387953f,  0.96592583f,  0.99144486f
};
constexpr float SIN48[48] = {
  0.0f,        0.13052619f,  0.25881905f,  0.38268343f,  0.5f,         0.60876143f,
  0.70710678f, 0.79335334f,  0.86602540f,  0.92387953f,  0.96592583f,  0.99144486f,
  1.0f,        0.99144486f,  0.96592583f,  0.92387953f,  0.86602540f,  0.79335334f,
  0.70710678f, 0.60876143f,  0.5f,         0.38268343f,  0.25881905f,  0.13052619f,
  0.0f,       -0.13052619f, -0.25881905f, -0.38268343f, -0.5f,        -0.60876143f,
 -0.70710678f,-0.79335334f, -0.86602540f, -0.92387953f, -0.96592583f, -0.99144486f,
 -1.0f,       -0.99144486f, -0.96592583f, -0.92387953f, -0.86602540f, -0.79335334f,
 -0.70710678f,-0.60876143f, -0.5f,        -0.38268343f, -0.25881905f, -0.13052619f
};

constexpr float W8R_TAB[8] = {1.0f, 0.70710678f, 0.0f, -0.70710678f, -1.0f, -0.70710678f, 0.0f, 0.70710678f};
constexpr float W8I_TAB[8] = {0.0f, 0.70710678f, 1.0f,  0.70710678f,  0.0f, -0.70710678f, -1.0f, -0.70710678f};

__device__ __forceinline__ unsigned bf16_rne(float x) {
  unsigned u = __float_as_uint(x);
  u += 0x7FFFu + ((u >> 16) & 1u);
  return u >> 16;
}

__device__ __forceinline__ float4 ld_f4(const float* p) {
  return *reinterpret_cast<const float4*>(p);
}

#define FMA4(acc, v, s) \
  do { (acc).x += (v).x * (s); (acc).y += (v).y * (s); \
       (acc).z += (v).z * (s); (acc).w += (v).w * (s); } while (0)

__global__ __launch_bounds__(256, 3)
void bd2af_kernel(const float* __restrict__ xr, const float* __restrict__ xi,
                  unsigned* __restrict__ out, int nbc) {
  __shared__ __align__(16) float Ar[64 * RP], Ai[64 * RP];   // X -> Y -> out staging
  __shared__ __align__(16) float Br[64 * RP], Bi[64 * RP];   // T1 -> S buffer
  __shared__ float w8r[8], w8i[8];

  const int tid = threadIdx.x;
  const int bc = blockIdx.x;
  if (bc >= nbc) return;

  if (tid < 8) { w8r[tid] = W8R_TAB[tid]; w8i[tid] = W8I_TAB[tid]; }

  // ---- global -> LDS (rows of 48 padded to 52) ----
  {
    const float4* gr = reinterpret_cast<const float4*>(xr) + (size_t)bc * 768;
    const float4* gi = reinterpret_cast<const float4*>(xi) + (size_t)bc * 768;
#pragma unroll
    for (int k = 0; k < 3; ++k) {
      const int o4 = tid + 256 * k;
      const float4 vr = gr[o4];
      const float4 vi = gi[o4];
      const int o = o4 * 4;
      const int row = o / 48;
      const int a = row * RP + (o - row * 48);
      *reinterpret_cast<float4*>(&Ar[a]) = vr;
      *reinterpret_cast<float4*>(&Ai[a]) = vi;
    }
  }
  __syncthreads();

  const int c  = tid & 3;          // t/freq chunk
  const int t0 = c * 12;
  const int p  = (tid >> 2) & 1;
  const int vq = (tid >> 3) & 3;
  const int hq = tid >> 5;

  // ---- V pass: T1[H][v'][p][t] = sum_V X[H][V][p][t] * i^(V*v') ----
  {
    float4 ar0{0,0,0,0}, ar1{0,0,0,0}, ar2{0,0,0,0};
    float4 ai0{0,0,0,0}, ai1{0,0,0,0}, ai2{0,0,0,0};
#pragma unroll
    for (int V = 0; V < 4; ++V) {
      const int m = (V * vq) & 3;
      const float wr = (m == 0) ? 1.f : ((m == 2) ? -1.f : 0.f);
      const float wi = (m == 1) ? 1.f : ((m == 3) ? -1.f : 0.f);
      const int rowi = (hq * 4 + V) * 2 + p;
      const float* sr = &Ar[rowi * RP + t0];
      const float* si = &Ai[rowi * RP + t0];
      const float4 yr0 = ld_f4(sr), yr1 = ld_f4(sr + 4), yr2 = ld_f4(sr + 8);
      const float4 yi0 = ld_f4(si), yi1 = ld_f4(si + 4), yi2 = ld_f4(si + 8);
      FMA4(ar0, yr0, wr); FMA4(ar0, yi0, -wi);
      FMA4(ar1, yr1, wr); FMA4(ar1, yi1, -wi);
      FMA4(ar2, yr2, wr); FMA4(ar2, yi2, -wi);
      FMA4(ai0, yr0, wi); FMA4(ai0, yi0, wr);
      FMA4(ai1, yr1, wi); FMA4(ai1, yi1, wr);
      FMA4(ai2, yr2, wi); FMA4(ai2, yi2, wr);
    }
    const int rowo = (hq * 4 + vq) * 2 + p;
    float* dr = &Br[rowo * RP + t0];
    float* di = &Bi[rowo * RP + t0];
    *reinterpret_cast<float4*>(dr)     = ar0;
    *reinterpret_cast<float4*>(dr + 4) = ar1;
    *reinterpret_cast<float4*>(dr + 8) = ar2;
    *reinterpret_cast<float4*>(di)     = ai0;
    *reinterpret_cast<float4*>(di + 4) = ai1;
    *reinterpret_cast<float4*>(di + 8) = ai2;
  }
  __syncthreads();

  // ---- H pass: Y[h'][v'][p][t] = (-1)^{h'+v'} * sum_H T1[H][v'][p][t] * w8[(H*h')%8] ----
  {
    float4 ar0{0,0,0,0}, ar1{0,0,0,0}, ar2{0,0,0,0};
    float4 ai0{0,0,0,0}, ai1{0,0,0,0}, ai2{0,0,0,0};
#pragma unroll
    for (int H = 0; H < 8; ++H) {
      const int m = (H * hq) & 7;
      const float wr = w8r[m];
      const float wi = w8i[m];
      const int rowi = (H * 4 + vq) * 2 + p;
      const float* sr = &Br[rowi * RP + t0];
      const float* si = &Bi[rowi * RP + t0];
      const float4 yr0 = ld_f4(sr), yr1 = ld_f4(sr + 4), yr2 = ld_f4(sr + 8);
      const float4 yi0 = ld_f4(si), yi1 = ld_f4(si + 4), yi2 = ld_f4(si + 8);
      FMA4(ar0, yr0, wr); FMA4(ar0, yi0, -wi);
      FMA4(ar1, yr1, wr); FMA4(ar1, yi1, -wi);
      FMA4(ar2, yr2, wr); FMA4(ar2, yi2, -wi);
      FMA4(ai0, yr0, wi); FMA4(ai0, yi0, wr);
      FMA4(ai1, yr1, wi); FMA4(ai1, yi1, wr);
      FMA4(ai2, yr2, wi); FMA4(ai2, yi2, wr);
    }
    const float sgn = ((hq + vq) & 1) ? -1.f : 1.f;
    const int rowo = (hq * 4 + vq) * 2 + p;
    float* dr = &Ar[rowo * RP + t0];
    float* di = &Ai[rowo * RP + t0];
    const float4 sr0{ar0.x*sgn, ar0.y*sgn, ar0.z*sgn, ar0.w*sgn};
    const float4 sr1{ar1.x*sgn, ar1.y*sgn, ar1.z*sgn, ar1.w*sgn};
    const float4 sr2{ar2.x*sgn, ar2.y*sgn, ar2.z*sgn, ar2.w*sgn};
    const float4 si0{ai0.x*sgn, ai0.y*sgn, ai0.z*sgn, ai0.w*sgn};
    const float4 si1{ai1.x*sgn, ai1.y*sgn, ai1.z*sgn, ai1.w*sgn};
    const float4 si2{ai2.x*sgn, ai2.y*sgn, ai2.z*sgn, ai2.w*sgn};
    *reinterpret_cast<float4*>(dr)     = sr0;
    *reinterpret_cast<float4*>(dr + 4) = sr1;
    *reinterpret_cast<float4*>(dr + 8) = sr2;
    *reinterpret_cast<float4*>(di)     = si0;
    *reinterpret_cast<float4*>(di + 4) = si1;
    *reinterpret_cast<float4*>(di + 8) = si2;
  }
  __syncthreads();

  // ---- time DFT, radix 48 = 4 x 12 ----
  // out[12c+j] = sum_b (-i)^{bc} * W48^{bj} * S[b][j],  S[b][j] = sum_a z[4a+b] W12^{aj}
  float* Sr = Br;   // S overlays T1 (dead): [row][b*12+j], stride SP=49
  float* Si = Bi;

  // Phase A: thread (r, b) computes S[b][0..11] for its row (const-indexed arrays only)
  {
    const int r = tid >> 2;
    const int b = tid & 3;
    float z_r[12], z_i[12];
#pragma unroll
    for (int a = 0; a < 12; ++a) {
      z_r[a] = Ar[r * RP + 4 * a + b];
      z_i[a] = Ai[r * RP + 4 * a + b];
    }
    float s_r[12], s_i[12];
#pragma unroll
    for (int j = 0; j < 12; ++j) { s_r[j] = 0.f; s_i[j] = 0.f; }
#pragma unroll
    for (int a = 0; a < 12; ++a) {
#pragma unroll
      for (int j = 0; j < 12; ++j) {
        const int k = (4 * a * j) % 48;
        const float wr = COS48[k];
        const float wi = -SIN48[k];
        s_r[j] += z_r[a] * wr - z_i[a] * wi;
        s_i[j] += z_r[a] * wi + z_i[a] * wr;
      }
    }
#pragma unroll
    for (int j = 0; j < 12; ++j) {
      Sr[r * SP + b * 12 + j] = s_r[j];
      Si[r * SP + b * 12 + j] = s_i[j];
    }
  }
  __syncthreads();

  // Phase B: thread (r, c) combines 4 b-slices into out[12c+j], packs bf16
  {
    const int r = tid >> 2;
    const float a1r = (c == 0) ? 1.f : ((c == 2) ? -1.f : 0.f);
    const float a1i = (c == 1) ? -1.f : ((c == 3) ? 1.f : 0.f);
    const float s2  = (c & 1) ? -1.f : 1.f;
    float or_[12], oi_[12];
#pragma unroll
    for (int j = 0; j < 12; ++j) {
      or_[j] = Sr[r * SP + j];
      oi_[j] = Si[r * SP + j];
    }
#pragma unroll
    for (int j = 0; j < 12; ++j) {   // b = 1: (-i)^c * S1*W48^j
      const float wr = COS48[j], wi = -SIN48[j];
      const float sr = Sr[r * SP + 12 + j], si = Si[r * SP + 12 + j];
      const float tr = sr * wr - si * wi, ti = sr * wi + si * wr;
      or_[j] += a1r * tr - a1i * ti;
      oi_[j] += a1r * ti + a1i * tr;
    }
#pragma unroll
    for (int j = 0; j < 12; ++j) {   // b = 2: (-1)^c * S2*W48^{2j}
      const float wr = COS48[(2 * j) % 48], wi = -SIN48[(2 * j) % 48];
      const float sr = Sr[r * SP + 24 + j], si = Si[r * SP + 24 + j];
      const float tr = sr * wr - si * wi, ti = sr * wi + si * wr;
      or_[j] += s2 * tr;
      oi_[j] += s2 * ti;
    }
#pragma unroll
    for (int j = 0; j < 12; ++j) {   // b = 3: (i)^c * S3*W48^{3j}
      const float wr = COS48[(3 * j) % 48], wi = -SIN48[(3 * j) % 48];
      const float sr = Sr[r * SP + 36 + j], si = Si[r * SP + 36 + j];
      const float tr = sr * wr - si * wi, ti = sr * wi + si * wr;
      or_[j] += a1r * tr + a1i * ti;
      oi_[j] += a1r * ti - a1i * tr;
    }
    unsigned* obuf = reinterpret_cast<unsigned*>(Ar);   // staging overlays Y (dead)
#pragma unroll
    for (int j = 0; j < 12; ++j) {
      const float s = (j & 1) ? -NORM : NORM;   // (-1)^f = (-1)^j since f = 12c+j
      obuf[r * 48 + c * 12 + j] = bf16_rne(oi_[j] * s) | (bf16_rne(or_[j] * s) << 16);
    }
  }
  __syncthreads();

  // ---- coalesced store: 3072 dwords = 768 uint4 per block ----
  {
    const uint4* ob = reinterpret_cast<const uint4*>(Ar);
    uint4* og = reinterpret_cast<uint4*>(out) + (size_t)bc * 768;
#pragma unroll
    for (int k = 0; k < 3; ++k) {
      const int o4 = tid + 256 * k;
      const uint4 v = ob[o4];
      og[o4] = v;
    }
  }
}

} // namespace

extern "C" void kernel_launch(void* const* d_in, const int* in_sizes, int n_in,
                              void* d_out, int out_size, void* d_ws, size_t ws_size,
                              hipStream_t stream) {
  const float* xr = (const float*)d_in[0];   // dict order: x_real first
  const float* xi = (const float*)d_in[1];
  unsigned* out = (unsigned*)d_out;          // dword = im(bf16) | re(bf16)<<16
  const int nbc = in_sizes[0] / 3072;        // 8192 blocks of (8*4*2*48)
  bd2af_kernel<<<nbc, 256, 0, stream>>>(xr, xi, out, nbc);
}

// Round 18
// 72.295 us; speedup vs baseline: 6.1924x; 1.5738x over previous
//
#include <hip/hip_runtime.h>

// BeamDelay2AntFreq: (256,32,8,4,2,48) complex -> ifft4(V) -> ifft8(H) -> fft48(t),
// fftshifts folded into (-1)^{h+v+f}; ortho norm 1/sqrt(1536).
// OUTPUT: interleaved bf16 pairs IMAG FIRST: dword = im | (re<<16), (b,c,row,f) order.
// R18: in-register radix FFTs. V: global->reg 4-pt iFFT (no staging LDS).
// H: 8-pt iFFT in-place in LDS (128 threads). A: radix-12 (3xDFT4+tw+4xDFT3).
// B: combine + DIRECT coalesced global store (no out-staging). 3 barriers.

namespace {

constexpr int RP = 52;       // T buffer row stride (floats)
constexpr int SP = 49;       // S buffer row stride
constexpr float NORM = 0.02551551815399144f;  // 1/sqrt(1536)
constexpr float R2  = 0.70710678f;            // 1/sqrt(2)
constexpr float C30 = 0.86602540f;            // cos(30) = sin(60)

constexpr float COS48[48] = {
  1.0f,        0.99144486f,  0.96592583f,  0.92387953f,  0.86602540f,  0.79335334f,
  0.70710678f, 0.60876143f,  0.5f,         0.38268343f,  0.25881905f,  0.13052619f,
  0.0f,       -0.13052619f, -0.25881905f, -0.38268343f, -0.5f,        -0.60876143f,
 -0.70710678f,-0.79335334f, -0.86602540f, -0.92387953f, -0.96592583f, -0.99144486f,
 -1.0f,       -0.99144486f, -0.96592583f, -0.92387953f, -0.86602540f, -0.79335334f,
 -0.70710678f,-0.60876143f, -0.5f,        -0.38268343f, -0.25881905f, -0.13052619f,
  0.0f,        0.13052619f,  0.25881905f,  0.38268343f,  0.5f,         0.60876143f,
  0.70710678f, 0.79335334f,  0.86602540f,  0.92387953f,  0.96592583f,  0.99144486f
};
constexpr float SIN48[48] = {
  0.0f,        0.13052619f,  0.25881905f,  0.38268343f,  0.5f,         0.60876143f,
  0.70710678f, 0.79335334f,  0.86602540f,  0.92387953f,  0.96592583f,  0.99144486f,
  1.0f,        0.99144486f,  0.96592583f,  0.92387953f,  0.86602540f,  0.79335334f,
  0.70710678f, 0.60876143f,  0.5f,         0.38268343f,  0.25881905f,  0.13052619f,
  0.0f,       -0.13052619f, -0.25881905f, -0.38268343f, -0.5f,        -0.60876143f,
 -0.70710678f,-0.79335334f, -0.86602540f, -0.92387953f, -0.96592583f, -0.99144486f,
 -1.0f,       -0.99144486f, -0.96592583f, -0.92387953f, -0.86602540f, -0.79335334f,
 -0.70710678f,-0.60876143f, -0.5f,        -0.38268343f, -0.25881905f, -0.13052619f
};

__device__ __forceinline__ unsigned bf16_rne(float x) {
  unsigned u = __float_as_uint(x);
  u += 0x7FFFu + ((u >> 16) & 1u);
  return u >> 16;
}

__global__ __launch_bounds__(256, 3)
void bd2af_kernel(const float* __restrict__ xr, const float* __restrict__ xi,
                  unsigned* __restrict__ out, int nbc) {
  __shared__ float Tr[64 * RP], Ti[64 * RP];   // T1 -> Y (in-place)
  __shared__ float Sr[64 * SP], Si[64 * SP];   // S buffer

  const int tid = threadIdx.x;
  const int bc = blockIdx.x;
  if (bc >= nbc) return;

  const float* gxr = xr + (size_t)bc * 3072;
  const float* gxi = xi + (size_t)bc * 3072;

  // ---- V phase: global -> reg, 4-pt inverse FFT (kernel i^{V v'}), write T1 ----
  {
    const int hq = tid >> 5;           // 0..7
    const int p  = (tid >> 4) & 1;
    const int tc = tid & 15;
    const int t0 = 3 * tc;
    const int rowb = hq * 8 + p;       // row = rowb + 2V
#pragma unroll
    for (int k = 0; k < 3; ++k) {
      const int tt = t0 + k;
      const float x0r = gxr[(rowb + 0) * 48 + tt], x0i = gxi[(rowb + 0) * 48 + tt];
      const float x1r = gxr[(rowb + 2) * 48 + tt], x1i = gxi[(rowb + 2) * 48 + tt];
      const float x2r = gxr[(rowb + 4) * 48 + tt], x2i = gxi[(rowb + 4) * 48 + tt];
      const float x3r = gxr[(rowb + 6) * 48 + tt], x3i = gxi[(rowb + 6) * 48 + tt];
      const float e0r = x0r + x2r, e0i = x0i + x2i;
      const float e1r = x0r - x2r, e1i = x0i - x2i;
      const float o0r = x1r + x3r, o0i = x1i + x3i;
      const float o1r = x1r - x3r, o1i = x1i - x3i;
      Tr[(rowb + 0) * RP + tt] = e0r + o0r;  Ti[(rowb + 0) * RP + tt] = e0i + o0i;
      Tr[(rowb + 2) * RP + tt] = e1r - o1i;  Ti[(rowb + 2) * RP + tt] = e1i + o1r;  // +i*o1
      Tr[(rowb + 4) * RP + tt] = e0r - o0r;  Ti[(rowb + 4) * RP + tt] = e0i - o0i;
      Tr[(rowb + 6) * RP + tt] = e1r + o1i;  Ti[(rowb + 6) * RP + tt] = e1i - o1r;  // -i*o1
    }
  }
  __syncthreads();

  // ---- H phase (128 threads): 8-pt inverse FFT in-place, with (-1)^{h'+v'} ----
  if (tid < 128) {
    const int vq = tid >> 5;           // 0..3
    const int p  = (tid >> 4) & 1;
    const int tc = tid & 15;
    const int t0 = 3 * tc;
    const int rowb = 2 * vq + p;       // row = rowb + 8H
    const float sgnE = (vq & 1) ? -1.f : 1.f;   // (-1)^{h'+vq}, h' even
    const float sgnO = -sgnE;                   // h' odd
#pragma unroll
    for (int k = 0; k < 3; ++k) {
      const int tt = t0 + k;
      const float t0r = Tr[(rowb +  0) * RP + tt], t0i = Ti[(rowb +  0) * RP + tt];
      const float t1r = Tr[(rowb +  8) * RP + tt], t1i = Ti[(rowb +  8) * RP + tt];
      const float t2r = Tr[(rowb + 16) * RP + tt], t2i = Ti[(rowb + 16) * RP + tt];
      const float t3r = Tr[(rowb + 24) * RP + tt], t3i = Ti[(rowb + 24) * RP + tt];
      const float t4r = Tr[(rowb + 32) * RP + tt], t4i = Ti[(rowb + 32) * RP + tt];
      const float t5r = Tr[(rowb + 40) * RP + tt], t5i = Ti[(rowb + 40) * RP + tt];
      const float t6r = Tr[(rowb + 48) * RP + tt], t6i = Ti[(rowb + 48) * RP + tt];
      const float t7r = Tr[(rowb + 56) * RP + tt], t7i = Ti[(rowb + 56) * RP + tt];
      // evens T0,T2,T4,T6 -> inverse DFT4
      const float e0r = t0r + t4r, e0i = t0i + t4i, e1r = t0r - t4r, e1i = t0i - t4i;
      const float o0r = t2r + t6r, o0i = t2i + t6i, o1r = t2r - t6r, o1i = t2i - t6i;
      const float E0r = e0r + o0r, E0i = e0i + o0i;
      const float E2r = e0r - o0r, E2i = e0i - o0i;
      const float E1r = e1r - o1i, E1i = e1i + o1r;   // e1 + i o1
      const float E3r = e1r + o1i, E3i = e1i - o1r;   // e1 - i o1
      // odds T1,T3,T5,T7 -> inverse DFT4
      const float f0r = t1r + t5r, f0i = t1i + t5i, f1r = t1r - t5r, f1i = t1i - t5i;
      const float g0r = t3r + t7r, g0i = t3i + t7i, g1r = t3r - t7r, g1i = t3i - t7i;
      const float O0r = f0r + g0r, O0i = f0i + g0i;
      const float O2r = f0r - g0r, O2i = f0i - g0i;
      const float O1r = f1r - g1i, O1i = f1i + g1r;
      const float O3r = f1r + g1i, O3i = f1i - g1r;
      // twiddles: W1 = w8^1*O1 = (1+i)/sqrt2 * O1 ; W3 = w8^3*O3 = (-1+i)/sqrt2 * O3
      const float W1r = R2 * (O1r - O1i), W1i = R2 * (O1r + O1i);
      const float W3r = R2 * (-O3r - O3i), W3i = R2 * (O3r - O3i);
      // outputs, with per-row sign
      Tr[(rowb +  0) * RP + tt] = sgnE * (E0r + O0r);  Ti[(rowb +  0) * RP + tt] = sgnE * (E0i + O0i);
      Tr[(rowb + 32) * RP + tt] = sgnE * (E0r - O0r);  Ti[(rowb + 32) * RP + tt] = sgnE * (E0i - O0i);
      Tr[(rowb + 16) * RP + tt] = sgnE * (E2r - O2i);  Ti[(rowb + 16) * RP + tt] = sgnE * (E2i + O2r);  // +i O2
      Tr[(rowb + 48) * RP + tt] = sgnE * (E2r + O2i);  Ti[(rowb + 48) * RP + tt] = sgnE * (E2i - O2r);  // -i O2
      Tr[(rowb +  8) * RP + tt] = sgnO * (E1r + W1r);  Ti[(rowb +  8) * RP + tt] = sgnO * (E1i + W1i);
      Tr[(rowb + 40) * RP + tt] = sgnO * (E1r - W1r);  Ti[(rowb + 40) * RP + tt] = sgnO * (E1i - W1i);
      Tr[(rowb + 24) * RP + tt] = sgnO * (E3r + W3r);  Ti[(rowb + 24) * RP + tt] = sgnO * (E3i + W3i);
      Tr[(rowb + 56) * RP + tt] = sgnO * (E3r - W3r);  Ti[(rowb + 56) * RP + tt] = sgnO * (E3i - W3i);
    }
  }
  __syncthreads();

  // ---- Phase A: radix-12 DFT per (row, b): S[j] = sum_a z[a] W12^{aj} ----
  // a = 3a1+a2, j = j1+4j2: 3x(DFT4 kernel (-i)^{a1 j1}) -> tw W12^{a2 j1} -> 4x(DFT3)
  {
    const int r = tid >> 2;
    const int b = tid & 3;
    float zr[12], zi[12];
#pragma unroll
    for (int a = 0; a < 12; ++a) {
      zr[a] = Tr[r * RP + 4 * a + b];
      zi[a] = Ti[r * RP + 4 * a + b];
    }
    float h0r[3], h0i[3], h1r[3], h1i[3], h2r[3], h2i[3], h3r[3], h3i[3];
#pragma unroll
    for (int a2 = 0; a2 < 3; ++a2) {
      const float e0r = zr[a2] + zr[a2 + 6], e0i = zi[a2] + zi[a2 + 6];
      const float e1r = zr[a2] - zr[a2 + 6], e1i = zi[a2] - zi[a2 + 6];
      const float o0r = zr[a2 + 3] + zr[a2 + 9], o0i = zi[a2 + 3] + zi[a2 + 9];
      const float o1r = zr[a2 + 3] - zr[a2 + 9], o1i = zi[a2 + 3] - zi[a2 + 9];
      h0r[a2] = e0r + o0r;  h0i[a2] = e0i + o0i;
      h2r[a2] = e0r - o0r;  h2i[a2] = e0i - o0i;
      h1r[a2] = e1r + o1i;  h1i[a2] = e1i - o1r;   // e1 - i o1 (forward)
      h3r[a2] = e1r - o1i;  h3i[a2] = e1i + o1r;   // e1 + i o1
    }
    // twiddles W12^{a2*j1}: a2=1: j1=1: W12^1=(C30,-0.5); j1=2: W12^2=(0.5,-C30); j1=3: -i
    {
      float a, bb;
      a = h1r[1]; bb = h1i[1];
      h1r[1] = C30 * a + 0.5f * bb;  h1i[1] = C30 * bb - 0.5f * a;
      a = h2r[1]; bb = h2i[1];
      h2r[1] = 0.5f * a + C30 * bb;  h2i[1] = 0.5f * bb - C30 * a;
      a = h3r[1]; bb = h3i[1];
      h3r[1] = bb;                   h3i[1] = -a;
      // a2=2: j1=1: W12^2; j1=2: W12^4=(-0.5,-C30); j1=3: -1
      a = h1r[2]; bb = h1i[2];
      h1r[2] = 0.5f * a + C30 * bb;  h1i[2] = 0.5f * bb - C30 * a;
      a = h2r[2]; bb = h2i[2];
      h2r[2] = -0.5f * a + C30 * bb; h2i[2] = -0.5f * bb - C30 * a;
      h3r[2] = -h3r[2];              h3i[2] = -h3i[2];
    }
    // DFT-3 over a2 for each j1 -> S[j1 + 4*j2]
    float s_r[12], s_i[12];
#define DFT3(J1, HR, HI)                                                    \
    {                                                                       \
      const float tr_ = HR[1] + HR[2], ti_ = HI[1] + HI[2];                 \
      const float dr_ = HR[1] - HR[2], di_ = HI[1] - HI[2];                 \
      const float mr_ = HR[0] - 0.5f * tr_, mi_ = HI[0] - 0.5f * ti_;       \
      const float wr_ = C30 * dr_, wi_ = C30 * di_;                         \
      s_r[J1]     = HR[0] + tr_;  s_i[J1]     = HI[0] + ti_;                \
      s_r[J1 + 4] = mr_ + wi_;    s_i[J1 + 4] = mi_ - wr_;                  \
      s_r[J1 + 8] = mr_ - wi_;    s_i[J1 + 8] = mi_ + wr_;                  \
    }
    DFT3(0, h0r, h0i)
    DFT3(1, h1r, h1i)
    DFT3(2, h2r, h2i)
    DFT3(3, h3r, h3i)
#undef DFT3
#pragma unroll
    for (int j = 0; j < 12; ++j) {
      Sr[r * SP + b * 12 + j] = s_r[j];
      Si[r * SP + b * 12 + j] = s_i[j];
    }
  }
  __syncthreads();

  // ---- Phase B: combine 4 b-slices with W48 twiddles, pack, direct store ----
  {
    const int r = tid >> 2;
    const int c = tid & 3;
    const float a1r = (c == 0) ? 1.f : ((c == 2) ? -1.f : 0.f);
    const float a1i = (c == 1) ? -1.f : ((c == 3) ? 1.f : 0.f);
    const float s2  = (c & 1) ? -1.f : 1.f;
    float or_[12], oi_[12];
#pragma unroll
    for (int j = 0; j < 12; ++j) {
      or_[j] = Sr[r * SP + j];
      oi_[j] = Si[r * SP + j];
    }
#pragma unroll
    for (int j = 0; j < 12; ++j) {   // b = 1: (-i)^c * S1*W48^j
      const float wr = COS48[j], wi = -SIN48[j];
      const float sr = Sr[r * SP + 12 + j], si = Si[r * SP + 12 + j];
      const float tr = sr * wr - si * wi, ti = sr * wi + si * wr;
      or_[j] += a1r * tr - a1i * ti;
      oi_[j] += a1r * ti + a1i * tr;
    }
#pragma unroll
    for (int j = 0; j < 12; ++j) {   // b = 2: (-1)^c * S2*W48^{2j}
      const float wr = COS48[(2 * j) % 48], wi = -SIN48[(2 * j) % 48];
      const float sr = Sr[r * SP + 24 + j], si = Si[r * SP + 24 + j];
      const float tr = sr * wr - si * wi, ti = sr * wi + si * wr;
      or_[j] += s2 * tr;
      oi_[j] += s2 * ti;
    }
#pragma unroll
    for (int j = 0; j < 12; ++j) {   // b = 3: (i)^c * S3*W48^{3j}
      const float wr = COS48[(3 * j) % 48], wi = -SIN48[(3 * j) % 48];
      const float sr = Sr[r * SP + 36 + j], si = Si[r * SP + 36 + j];
      const float tr = sr * wr - si * wi, ti = sr * wi + si * wr;
      or_[j] += a1r * tr + a1i * ti;
      oi_[j] += a1r * ti - a1i * tr;
    }
    unsigned pk[12];
#pragma unroll
    for (int j = 0; j < 12; ++j) {
      const float s = (j & 1) ? -NORM : NORM;   // (-1)^f = (-1)^j since f = 12c+j
      pk[j] = bf16_rne(oi_[j] * s) | (bf16_rne(or_[j] * s) << 16);
    }
    unsigned* og = out + (size_t)bc * 3072 + r * 48 + c * 12;
    *reinterpret_cast<uint4*>(og)     = make_uint4(pk[0], pk[1], pk[2],  pk[3]);
    *reinterpret_cast<uint4*>(og + 4) = make_uint4(pk[4], pk[5], pk[6],  pk[7]);
    *reinterpret_cast<uint4*>(og + 8) = make_uint4(pk[8], pk[9], pk[10], pk[11]);
  }
}

} // namespace

extern "C" void kernel_launch(void* const* d_in, const int* in_sizes, int n_in,
                              void* d_out, int out_size, void* d_ws, size_t ws_size,
                              hipStream_t stream) {
  const float* xr = (const float*)d_in[0];   // dict order: x_real first
  const float* xi = (const float*)d_in[1];
  unsigned* out = (unsigned*)d_out;          // dword = im(bf16) | re(bf16)<<16
  const int nbc = in_sizes[0] / 3072;        // 8192 blocks of (8*4*2*48)
  bd2af_kernel<<<nbc, 256, 0, stream>>>(xr, xi, out, nbc);
}

// Round 19
// 63.382 us; speedup vs baseline: 7.0632x; 1.1406x over previous
//
#include <hip/hip_runtime.h>

// BeamDelay2AntFreq: (256,32,8,4,2,48) complex -> ifft4(V) -> ifft8(H) -> fft48(t),
// fftshifts folded into (-1)^{h+v+f}; ortho norm 1/sqrt(1536).
// OUTPUT: interleaved bf16 pairs IMAG FIRST: dword = im | (re<<16), (b,c,row,f) order.
// R19: S buffer overlays T in-place (rows wave-private in phases A/B) -> LDS
// 51.7KB -> 25.1KB -> 6 blocks/CU; A->B barrier removed (wave-internal dep);
// RP=49 odd stride (bank-coprime). 2 barriers total.

namespace {

constexpr int RP = 49;       // T/S shared row stride (floats); span 48 < 49 => row-private
constexpr float NORM = 0.02551551815399144f;  // 1/sqrt(1536)
constexpr float R2  = 0.70710678f;            // 1/sqrt(2)
constexpr float C30 = 0.86602540f;            // cos(30)

constexpr float COS48[48] = {
  1.0f,        0.99144486f,  0.96592583f,  0.92387953f,  0.86602540f,  0.79335334f,
  0.70710678f, 0.60876143f,  0.5f,         0.38268343f,  0.25881905f,  0.13052619f,
  0.0f,       -0.13052619f, -0.25881905f, -0.38268343f, -0.5f,        -0.60876143f,
 -0.70710678f,-0.79335334f, -0.86602540f, -0.92387953f, -0.96592583f, -0.99144486f,
 -1.0f,       -0.99144486f, -0.96592583f, -0.92387953f, -0.86602540f, -0.79335334f,
 -0.70710678f,-0.60876143f, -0.5f,        -0.38268343f, -0.25881905f, -0.13052619f,
  0.0f,        0.13052619f,  0.25881905f,  0.38268343f,  0.5f,         0.60876143f,
  0.70710678f, 0.79335334f,  0.86602540f,  0.92387953f,  0.96592583f,  0.99144486f
};
constexpr float SIN48[48] = {
  0.0f,        0.13052619f,  0.25881905f,  0.38268343f,  0.5f,         0.60876143f,
  0.70710678f, 0.79335334f,  0.86602540f,  0.92387953f,  0.96592583f,  0.99144486f,
  1.0f,        0.99144486f,  0.96592583f,  0.92387953f,  0.86602540f,  0.79335334f,
  0.70710678f, 0.60876143f,  0.5f,         0.38268343f,  0.25881905f,  0.13052619f,
  0.0f,       -0.13052619f, -0.25881905f, -0.38268343f, -0.5f,        -0.60876143f,
 -0.70710678f,-0.79335334f, -0.86602540f, -0.92387953f, -0.96592583f, -0.99144486f,
 -1.0f,       -0.99144486f, -0.96592583f, -0.92387953f, -0.86602540f, -0.79335334f,
 -0.70710678f,-0.60876143f, -0.5f,        -0.38268343f, -0.25881905f, -0.13052619f
};

__device__ __forceinline__ unsigned bf16_rne(float x) {
  unsigned u = __float_as_uint(x);
  u += 0x7FFFu + ((u >> 16) & 1u);
  return u >> 16;
}

__global__ __launch_bounds__(256, 6)
void bd2af_kernel(const float* __restrict__ xr, const float* __restrict__ xi,
                  unsigned* __restrict__ out, int nbc) {
  __shared__ float Tr[64 * RP], Ti[64 * RP];   // X->T1->Y->S (all phases overlay)

  const int tid = threadIdx.x;
  const int bc = blockIdx.x;
  if (bc >= nbc) return;

  const float* gxr = xr + (size_t)bc * 3072;
  const float* gxi = xi + (size_t)bc * 3072;

  // ---- V phase: global -> reg, 4-pt inverse FFT (kernel i^{V v'}), write T1 ----
  {
    const int hq = tid >> 5;           // 0..7
    const int p  = (tid >> 4) & 1;
    const int tc = tid & 15;
    const int t0 = 3 * tc;
    const int rowb = hq * 8 + p;       // row = rowb + 2V
#pragma unroll
    for (int k = 0; k < 3; ++k) {
      const int tt = t0 + k;
      const float x0r = gxr[(rowb + 0) * 48 + tt], x0i = gxi[(rowb + 0) * 48 + tt];
      const float x1r = gxr[(rowb + 2) * 48 + tt], x1i = gxi[(rowb + 2) * 48 + tt];
      const float x2r = gxr[(rowb + 4) * 48 + tt], x2i = gxi[(rowb + 4) * 48 + tt];
      const float x3r = gxr[(rowb + 6) * 48 + tt], x3i = gxi[(rowb + 6) * 48 + tt];
      const float e0r = x0r + x2r, e0i = x0i + x2i;
      const float e1r = x0r - x2r, e1i = x0i - x2i;
      const float o0r = x1r + x3r, o0i = x1i + x3i;
      const float o1r = x1r - x3r, o1i = x1i - x3i;
      Tr[(rowb + 0) * RP + tt] = e0r + o0r;  Ti[(rowb + 0) * RP + tt] = e0i + o0i;
      Tr[(rowb + 2) * RP + tt] = e1r - o1i;  Ti[(rowb + 2) * RP + tt] = e1i + o1r;  // +i*o1
      Tr[(rowb + 4) * RP + tt] = e0r - o0r;  Ti[(rowb + 4) * RP + tt] = e0i - o0i;
      Tr[(rowb + 6) * RP + tt] = e1r + o1i;  Ti[(rowb + 6) * RP + tt] = e1i - o1r;  // -i*o1
    }
  }
  __syncthreads();

  // ---- H phase (128 threads): 8-pt inverse FFT in-place, with (-1)^{h'+v'} ----
  if (tid < 128) {
    const int vq = tid >> 5;           // 0..3
    const int p  = (tid >> 4) & 1;
    const int tc = tid & 15;
    const int t0 = 3 * tc;
    const int rowb = 2 * vq + p;       // row = rowb + 8H
    const float sgnE = (vq & 1) ? -1.f : 1.f;   // (-1)^{h'+vq}, h' even
    const float sgnO = -sgnE;                   // h' odd
#pragma unroll
    for (int k = 0; k < 3; ++k) {
      const int tt = t0 + k;
      const float t0r = Tr[(rowb +  0) * RP + tt], t0i = Ti[(rowb +  0) * RP + tt];
      const float t1r = Tr[(rowb +  8) * RP + tt], t1i = Ti[(rowb +  8) * RP + tt];
      const float t2r = Tr[(rowb + 16) * RP + tt], t2i = Ti[(rowb + 16) * RP + tt];
      const float t3r = Tr[(rowb + 24) * RP + tt], t3i = Ti[(rowb + 24) * RP + tt];
      const float t4r = Tr[(rowb + 32) * RP + tt], t4i = Ti[(rowb + 32) * RP + tt];
      const float t5r = Tr[(rowb + 40) * RP + tt], t5i = Ti[(rowb + 40) * RP + tt];
      const float t6r = Tr[(rowb + 48) * RP + tt], t6i = Ti[(rowb + 48) * RP + tt];
      const float t7r = Tr[(rowb + 56) * RP + tt], t7i = Ti[(rowb + 56) * RP + tt];
      // evens T0,T2,T4,T6 -> inverse DFT4
      const float e0r = t0r + t4r, e0i = t0i + t4i, e1r = t0r - t4r, e1i = t0i - t4i;
      const float o0r = t2r + t6r, o0i = t2i + t6i, o1r = t2r - t6r, o1i = t2i - t6i;
      const float E0r = e0r + o0r, E0i = e0i + o0i;
      const float E2r = e0r - o0r, E2i = e0i - o0i;
      const float E1r = e1r - o1i, E1i = e1i + o1r;   // e1 + i o1
      const float E3r = e1r + o1i, E3i = e1i - o1r;   // e1 - i o1
      // odds T1,T3,T5,T7 -> inverse DFT4
      const float f0r = t1r + t5r, f0i = t1i + t5i, f1r = t1r - t5r, f1i = t1i - t5i;
      const float g0r = t3r + t7r, g0i = t3i + t7i, g1r = t3r - t7r, g1i = t3i - t7i;
      const float O0r = f0r + g0r, O0i = f0i + g0i;
      const float O2r = f0r - g0r, O2i = f0i - g0i;
      const float O1r = f1r - g1i, O1i = f1i + g1r;
      const float O3r = f1r + g1i, O3i = f1i - g1r;
      // twiddles: W1 = (1+i)/sqrt2 * O1 ; W3 = (-1+i)/sqrt2 * O3
      const float W1r = R2 * (O1r - O1i), W1i = R2 * (O1r + O1i);
      const float W3r = R2 * (-O3r - O3i), W3i = R2 * (O3r - O3i);
      Tr[(rowb +  0) * RP + tt] = sgnE * (E0r + O0r);  Ti[(rowb +  0) * RP + tt] = sgnE * (E0i + O0i);
      Tr[(rowb + 32) * RP + tt] = sgnE * (E0r - O0r);  Ti[(rowb + 32) * RP + tt] = sgnE * (E0i - O0i);
      Tr[(rowb + 16) * RP + tt] = sgnE * (E2r - O2i);  Ti[(rowb + 16) * RP + tt] = sgnE * (E2i + O2r);
      Tr[(rowb + 48) * RP + tt] = sgnE * (E2r + O2i);  Ti[(rowb + 48) * RP + tt] = sgnE * (E2i - O2r);
      Tr[(rowb +  8) * RP + tt] = sgnO * (E1r + W1r);  Ti[(rowb +  8) * RP + tt] = sgnO * (E1i + W1i);
      Tr[(rowb + 40) * RP + tt] = sgnO * (E1r - W1r);  Ti[(rowb + 40) * RP + tt] = sgnO * (E1i - W1i);
      Tr[(rowb + 24) * RP + tt] = sgnO * (E3r + W3r);  Ti[(rowb + 24) * RP + tt] = sgnO * (E3i + W3i);
      Tr[(rowb + 56) * RP + tt] = sgnO * (E3r - W3r);  Ti[(rowb + 56) * RP + tt] = sgnO * (E3i - W3i);
    }
  }
  __syncthreads();

  // ---- Phase A: radix-12 DFT per (row, b); S overlays T row-in-place ----
  // Rows are wave-private (r = tid>>2; wave w owns rows 16w..16w+15): all lane
  // reads of row r issue before any lane writes (program order, in-order LDS
  // pipe) -> safe overlay, and phase B (same wave reads) needs NO barrier.
  {
    const int r = tid >> 2;
    const int b = tid & 3;
    float zr[12], zi[12];
#pragma unroll
    for (int a = 0; a < 12; ++a) {
      zr[a] = Tr[r * RP + 4 * a + b];
      zi[a] = Ti[r * RP + 4 * a + b];
    }
    float h0r[3], h0i[3], h1r[3], h1i[3], h2r[3], h2i[3], h3r[3], h3i[3];
#pragma unroll
    for (int a2 = 0; a2 < 3; ++a2) {
      const float e0r = zr[a2] + zr[a2 + 6], e0i = zi[a2] + zi[a2 + 6];
      const float e1r = zr[a2] - zr[a2 + 6], e1i = zi[a2] - zi[a2 + 6];
      const float o0r = zr[a2 + 3] + zr[a2 + 9], o0i = zi[a2 + 3] + zi[a2 + 9];
      const float o1r = zr[a2 + 3] - zr[a2 + 9], o1i = zi[a2 + 3] - zi[a2 + 9];
      h0r[a2] = e0r + o0r;  h0i[a2] = e0i + o0i;
      h2r[a2] = e0r - o0r;  h2i[a2] = e0i - o0i;
      h1r[a2] = e1r + o1i;  h1i[a2] = e1i - o1r;   // e1 - i o1 (forward)
      h3r[a2] = e1r - o1i;  h3i[a2] = e1i + o1r;   // e1 + i o1
    }
    {
      float a, bb;
      a = h1r[1]; bb = h1i[1];
      h1r[1] = C30 * a + 0.5f * bb;  h1i[1] = C30 * bb - 0.5f * a;
      a = h2r[1]; bb = h2i[1];
      h2r[1] = 0.5f * a + C30 * bb;  h2i[1] = 0.5f * bb - C30 * a;
      a = h3r[1]; bb = h3i[1];
      h3r[1] = bb;                   h3i[1] = -a;
      a = h1r[2]; bb = h1i[2];
      h1r[2] = 0.5f * a + C30 * bb;  h1i[2] = 0.5f * bb - C30 * a;
      a = h2r[2]; bb = h2i[2];
      h2r[2] = -0.5f * a + C30 * bb; h2i[2] = -0.5f * bb - C30 * a;
      h3r[2] = -h3r[2];              h3i[2] = -h3i[2];
    }
    float s_r[12], s_i[12];
#define DFT3(J1, HR, HI)                                                    \
    {                                                                       \
      const float tr_ = HR[1] + HR[2], ti_ = HI[1] + HI[2];                 \
      const float dr_ = HR[1] - HR[2], di_ = HI[1] - HI[2];                 \
      const float mr_ = HR[0] - 0.5f * tr_, mi_ = HI[0] - 0.5f * ti_;       \
      const float wr_ = C30 * dr_, wi_ = C30 * di_;                         \
      s_r[J1]     = HR[0] + tr_;  s_i[J1]     = HI[0] + ti_;                \
      s_r[J1 + 4] = mr_ + wi_;    s_i[J1 + 4] = mi_ - wr_;                  \
      s_r[J1 + 8] = mr_ - wi_;    s_i[J1 + 8] = mi_ + wr_;                  \
    }
    DFT3(0, h0r, h0i)
    DFT3(1, h1r, h1i)
    DFT3(2, h2r, h2i)
    DFT3(3, h3r, h3i)
#undef DFT3
#pragma unroll
    for (int j = 0; j < 12; ++j) {
      Tr[r * RP + b * 12 + j] = s_r[j];
      Ti[r * RP + b * 12 + j] = s_i[j];
    }
  }
  // NO barrier: phase B reads S rows written by the same wave.

  // ---- Phase B: combine 4 b-slices with W48 twiddles, pack, direct store ----
  {
    const int r = tid >> 2;
    const int c = tid & 3;
    const float a1r = (c == 0) ? 1.f : ((c == 2) ? -1.f : 0.f);
    const float a1i = (c == 1) ? -1.f : ((c == 3) ? 1.f : 0.f);
    const float s2  = (c & 1) ? -1.f : 1.f;
    float or_[12], oi_[12];
#pragma unroll
    for (int j = 0; j < 12; ++j) {
      or_[j] = Tr[r * RP + j];
      oi_[j] = Ti[r * RP + j];
    }
#pragma unroll
    for (int j = 0; j < 12; ++j) {   // b = 1: (-i)^c * S1*W48^j
      const float wr = COS48[j], wi = -SIN48[j];
      const float sr = Tr[r * RP + 12 + j], si = Ti[r * RP + 12 + j];
      const float tr = sr * wr - si * wi, ti = sr * wi + si * wr;
      or_[j] += a1r * tr - a1i * ti;
      oi_[j] += a1r * ti + a1i * tr;
    }
#pragma unroll
    for (int j = 0; j < 12; ++j) {   // b = 2: (-1)^c * S2*W48^{2j}
      const float wr = COS48[(2 * j) % 48], wi = -SIN48[(2 * j) % 48];
      const float sr = Tr[r * RP + 24 + j], si = Ti[r * RP + 24 + j];
      const float tr = sr * wr - si * wi, ti = sr * wi + si * wr;
      or_[j] += s2 * tr;
      oi_[j] += s2 * ti;
    }
#pragma unroll
    for (int j = 0; j < 12; ++j) {   // b = 3: (i)^c * S3*W48^{3j}
      const float wr = COS48[(3 * j) % 48], wi = -SIN48[(3 * j) % 48];
      const float sr = Tr[r * RP + 36 + j], si = Ti[r * RP + 36 + j];
      const float tr = sr * wr - si * wi, ti = sr * wi + si * wr;
      or_[j] += a1r * tr + a1i * ti;
      oi_[j] += a1r * ti - a1i * tr;
    }
    unsigned pk[12];
#pragma unroll
    for (int j = 0; j < 12; ++j) {
      const float s = (j & 1) ? -NORM : NORM;   // (-1)^f = (-1)^j since f = 12c+j
      pk[j] = bf16_rne(oi_[j] * s) | (bf16_rne(or_[j] * s) << 16);
    }
    unsigned* og = out + (size_t)bc * 3072 + r * 48 + c * 12;
    *reinterpret_cast<uint4*>(og)     = make_uint4(pk[0], pk[1], pk[2],  pk[3]);
    *reinterpret_cast<uint4*>(og + 4) = make_uint4(pk[4], pk[5], pk[6],  pk[7]);
    *reinterpret_cast<uint4*>(og + 8) = make_uint4(pk[8], pk[9], pk[10], pk[11]);
  }
}

} // namespace

extern "C" void kernel_launch(void* const* d_in, const int* in_sizes, int n_in,
                              void* d_out, int out_size, void* d_ws, size_t ws_size,
                              hipStream_t stream) {
  const float* xr = (const float*)d_in[0];   // dict order: x_real first
  const float* xi = (const float*)d_in[1];
  unsigned* out = (unsigned*)d_out;          // dword = im(bf16) | re(bf16)<<16
  const int nbc = in_sizes[0] / 3072;        // 8192 blocks of (8*4*2*48)
  bd2af_kernel<<<nbc, 256, 0, stream>>>(xr, xi, out, nbc);
}